// Round 1
// baseline (554.157 us; speedup 1.0000x reference)
//
#include <hip/hip_runtime.h>

// Problem constants (from reference):
//   bpe_features [B, LAYERS, L, D] fp32
//   layer_w      [LAYERS]          fp32
//   word_ids     [B, L]            int32 (word j covers tokens 2j, 2j+1)
//   out          [B, MAX_WORDS, D] fp32
#define BB 16
#define LAYERS 13
#define LL 512
#define DD 1024
#define WW 256   // MAX_WORDS

// One block per (b, word). 256 threads, each owns a float4 slice of D.
// Memory-bound kernel: reads bpe_features exactly once (436 MB), coalesced
// 16 B/lane. Softmax over the 13 layer weights is recomputed per thread in
// registers (negligible vs. 104 KB of global loads per block).
__global__ __launch_bounds__(256) void MorphologicalTagger_13657996001460_kernel(
    const float* __restrict__ bpe,       // [BB, LAYERS, LL, DD]
    const float* __restrict__ layer_w,   // [LAYERS]
    const int*   __restrict__ word_ids,  // [BB, LL]
    float*       __restrict__ out)       // [BB, WW, DD]
{
    const int blk = blockIdx.x;
    const int b   = blk >> 8;    // / WW
    const int j   = blk & 255;   // % WW
    const int tid = threadIdx.x; // 0..255, float4 index into D

    // --- softmax over layer_w (13 scalars, L2-cached) ---
    float w[LAYERS];
    float m = -3.402823e38f;
#pragma unroll
    for (int l = 0; l < LAYERS; ++l) {
        w[l] = layer_w[l];
        m = fmaxf(m, w[l]);
    }
    float s = 0.f;
#pragma unroll
    for (int l = 0; l < LAYERS; ++l) {
        w[l] = expf(w[l] - m);
        s += w[l];
    }
    const float invs = 1.f / s;

    // --- segment membership for word j (tokens 2j, 2j+1) ---
    const int n0 = 2 * j;
    const int n1 = 2 * j + 1;
    const bool in0 = (word_ids[b * LL + n0] == j);
    const bool in1 = (word_ids[b * LL + n1] == j);
    const float cnt = (in0 ? 1.f : 0.f) + (in1 ? 1.f : 0.f);
    const float rcnt = 1.f / fmaxf(cnt, 1.f);

    // --- weighted sum over layers, both tokens of the word ---
    const int D4 = DD / 4;
    const float4* base =
        (const float4*)bpe + ((size_t)b * LAYERS * LL + (size_t)n0) * D4 + tid;
    const size_t layer_stride4 = (size_t)LL * D4;  // float4 stride between layers

    float4 acc = make_float4(0.f, 0.f, 0.f, 0.f);
#pragma unroll
    for (int l = 0; l < LAYERS; ++l) {
        const float wl = w[l] * invs;
        const float4* p = base + (size_t)l * layer_stride4;
        if (in0) {
            float4 x = p[0];
            acc.x += wl * x.x; acc.y += wl * x.y;
            acc.z += wl * x.z; acc.w += wl * x.w;
        }
        if (in1) {
            float4 x = p[D4];
            acc.x += wl * x.x; acc.y += wl * x.y;
            acc.z += wl * x.z; acc.w += wl * x.w;
        }
    }
    acc.x *= rcnt; acc.y *= rcnt; acc.z *= rcnt; acc.w *= rcnt;

    ((float4*)out)[((size_t)b * WW + j) * D4 + tid] = acc;
}

extern "C" void kernel_launch(void* const* d_in, const int* in_sizes, int n_in,
                              void* d_out, int out_size, void* d_ws, size_t ws_size,
                              hipStream_t stream) {
    const float* bpe      = (const float*)d_in[0];  // [16,13,512,1024]
    const float* layer_w  = (const float*)d_in[1];  // [13]
    const int*   word_ids = (const int*)d_in[2];    // [16,512]
    float* out = (float*)d_out;                     // [16,256,1024]

    dim3 grid(BB * WW);   // 4096 blocks
    dim3 block(256);
    MorphologicalTagger_13657996001460_kernel<<<grid, block, 0, stream>>>(
        bpe, layer_w, word_ids, out);
}

// Round 2
// 531.720 us; speedup vs baseline: 1.0422x; 1.0422x over previous
//
#include <hip/hip_runtime.h>

// Problem constants (from reference):
//   bpe_features [B, LAYERS, L, D] fp32
//   layer_w      [LAYERS]          fp32
//   word_ids     [B, L]            int32 (word j covers tokens 2j, 2j+1)
//   out          [B, MAX_WORDS, D] fp32
#define BB 16
#define LAYERS 13
#define LL 512
#define DD 1024
#define WW 256   // MAX_WORDS

typedef float f32x4 __attribute__((ext_vector_type(4)));

// One block per (b, word). 256 threads, each owns one float4 slice of D.
//
// Branch-free inner loop: the segment-membership scales (0/1) and the 1/count
// divisor factor OUT of the layer reduction:
//   out = rcnt * ( s0 * sum_l w_l * x[l, 2j] + s1 * sum_l w_l * x[l, 2j+1] )
// so the K-loop is 26 unconditional, independent float4 loads that the
// compiler can keep in flight together (the round-1 version had the loads
// inside exec-masked `if` regions -> one serialized vmcnt(0) per load ->
// latency-bound at 0.8 TB/s).
__global__ __launch_bounds__(256) void MorphologicalTagger_13657996001460_kernel(
    const float* __restrict__ bpe,       // [BB, LAYERS, LL, DD]
    const float* __restrict__ layer_w,   // [LAYERS]
    const int*   __restrict__ word_ids,  // [BB, LL]
    float*       __restrict__ out)       // [BB, WW, DD]
{
    const int blk = blockIdx.x;
    const int b   = blk >> 8;    // / WW
    const int j   = blk & 255;   // % WW
    const int tid = threadIdx.x; // 0..255, float4 index into D

    // --- softmax weights (unnormalized exp; 1/sum folded into final scale) ---
    float w[LAYERS];
    float m = -3.402823e38f;
#pragma unroll
    for (int l = 0; l < LAYERS; ++l) {
        w[l] = layer_w[l];
        m = fmaxf(m, w[l]);
    }
    float s = 0.f;
#pragma unroll
    for (int l = 0; l < LAYERS; ++l) {
        w[l] = __expf(w[l] - m);
        s += w[l];
    }
    const float invs = 1.f / s;

    // --- segment membership for word j (tokens 2j, 2j+1), folded to scales ---
    const int n0 = 2 * j;
    const bool in0 = (word_ids[b * LL + n0]     == j);
    const bool in1 = (word_ids[b * LL + n0 + 1] == j);
    const float cnt  = (in0 ? 1.f : 0.f) + (in1 ? 1.f : 0.f);
    const float rcnt = invs / fmaxf(cnt, 1.f);
    const float s0 = in0 ? rcnt : 0.f;
    const float s1 = in1 ? rcnt : 0.f;

    // --- branch-free weighted reduction over layers, both tokens ---
    const int D4 = DD / 4;
    const f32x4* p =
        (const f32x4*)bpe + ((size_t)(b * LAYERS) * LL + (size_t)n0) * D4 + tid;
    const size_t lstride = (size_t)LL * D4;  // float4 stride between layers

    f32x4 a0 = (f32x4)0.f;
    f32x4 a1 = (f32x4)0.f;
#pragma unroll
    for (int l = 0; l < LAYERS; ++l) {
        f32x4 x0 = __builtin_nontemporal_load(p + (size_t)l * lstride);
        f32x4 x1 = __builtin_nontemporal_load(p + (size_t)l * lstride + D4);
        a0 += w[l] * x0;
        a1 += w[l] * x1;
    }

    f32x4 r = s0 * a0 + s1 * a1;
    f32x4* op = (f32x4*)out + ((size_t)b * WW + j) * D4 + tid;
    __builtin_nontemporal_store(r, op);
}

extern "C" void kernel_launch(void* const* d_in, const int* in_sizes, int n_in,
                              void* d_out, int out_size, void* d_ws, size_t ws_size,
                              hipStream_t stream) {
    const float* bpe      = (const float*)d_in[0];  // [16,13,512,1024]
    const float* layer_w  = (const float*)d_in[1];  // [13]
    const int*   word_ids = (const int*)d_in[2];    // [16,512]
    float* out = (float*)d_out;                     // [16,256,1024]

    dim3 grid(BB * WW);   // 4096 blocks
    dim3 block(256);
    MorphologicalTagger_13657996001460_kernel<<<grid, block, 0, stream>>>(
        bpe, layer_w, word_ids, out);
}